// Round 1
// baseline (222.406 us; speedup 1.0000x reference)
//
#include <hip/hip_runtime.h>
#include <math.h>

#define Dd 32
#define Hh 128
#define NSTEPS 8
#define LOG2PI_F 1.8378770664093453f

__device__ __forceinline__ float fast_tanh(float x){
    // tanh(x) = 1 - 2/(exp(2x)+1); exp->inf and ->0 limits give +-1 correctly.
    float e = __expf(2.0f*x);
    return 1.0f - 2.0f*__builtin_amdgcn_rcpf(e + 1.0f);
}

// Qm[j,i] = W2[j,i] * (W1@W3)[i,j]  -> trace(J) = d2^T Qm d1
__global__ void qm_precompute(const float* __restrict__ W1, const float* __restrict__ W2,
                              const float* __restrict__ W3, float* __restrict__ Qm){
    int idx = blockIdx.x*256 + threadIdx.x;
    if (idx >= Hh*Hh) return;
    int j = idx >> 7;
    int i = idx & (Hh-1);
    float m = 0.f;
    #pragma unroll
    for (int d=0; d<Dd; ++d) m += W1[i*Dd+d]*W3[d*Hh+j];
    Qm[j*Hh+i] = m * W2[j*Hh+i];
}

__global__ __launch_bounds__(256,1) void vno_main(
    const float* __restrict__ x0, const float* __restrict__ W1, const float* __restrict__ u1,
    const float* __restrict__ b1, const float* __restrict__ W2, const float* __restrict__ b2,
    const float* __restrict__ W3, const float* __restrict__ b3, const float* __restrict__ prec,
    const float* __restrict__ Qm, int qm_valid, float* __restrict__ out, int B)
{
    const int tid  = threadIdx.x;
    const int b    = blockIdx.x;
    const int row  = tid >> 1;     // 0..127 : hidden row owned (2 threads per row)
    const int half = tid & 1;      // which 64-wide K-half
    const int kbase = half << 6;   // 0 or 64
    const int orow = tid & 31;     // output row for W3 partials
    const int kseg = tid >> 5;     // 0..7 : 16-wide K segment for W3

    __shared__ alignas(16) float h1s[Hh];
    __shared__ alignas(16) float d1s[Hh];
    __shared__ alignas(16) float h2s[Hh];
    __shared__ alignas(16) float xcur[Dd];
    __shared__ float ybase[Dd+2];
    __shared__ float karr[6][Dd+2];
    __shared__ float pout[8][Dd];
    __shared__ float tpart[4];
    __shared__ float logpx0_sh;

    // ---- register-resident weights (loaded once, reused for all 48 stages) ----
    float w1r[16], w2r[64], qr[64], w3r[16];
    {
        const float4* p = (const float4*)(W1 + row*Dd + (half<<4));
        #pragma unroll
        for (int q=0;q<4;++q){ float4 v=p[q]; w1r[4*q]=v.x; w1r[4*q+1]=v.y; w1r[4*q+2]=v.z; w1r[4*q+3]=v.w; }
    }
    {
        const float4* p = (const float4*)(W2 + row*Hh + kbase);
        #pragma unroll
        for (int q=0;q<16;++q){ float4 v=p[q]; w2r[4*q]=v.x; w2r[4*q+1]=v.y; w2r[4*q+2]=v.z; w2r[4*q+3]=v.w; }
    }
    {
        const float4* p = (const float4*)(W3 + orow*Hh + (kseg<<4));
        #pragma unroll
        for (int q=0;q<4;++q){ float4 v=p[q]; w3r[4*q]=v.x; w3r[4*q+1]=v.y; w3r[4*q+2]=v.z; w3r[4*q+3]=v.w; }
    }
    if (qm_valid){
        const float4* p = (const float4*)(Qm + row*Hh + kbase);
        #pragma unroll
        for (int q=0;q<16;++q){ float4 v=p[q]; qr[4*q]=v.x; qr[4*q+1]=v.y; qr[4*q+2]=v.z; qr[4*q+3]=v.w; }
    } else {
        // fallback: compute this thread's Qm slice directly
        float w3c[Dd];
        #pragma unroll
        for (int d=0; d<Dd; ++d) w3c[d] = W3[d*Hh + row];
        for (int k=0;k<64;++k){
            int i = kbase + k;
            const float4* w1p = (const float4*)(W1 + i*Dd);
            float m = 0.f;
            #pragma unroll
            for (int q=0;q<8;++q){ float4 v=w1p[q]; m += v.x*w3c[4*q] + v.y*w3c[4*q+1] + v.z*w3c[4*q+2] + v.w*w3c[4*q+3]; }
            qr[k] = m * W2[row*Hh + i];
        }
    }
    float u1r  = u1[row], b1r = b1[row], b2r = b2[row];
    float b3r  = (tid < Dd) ? b3[tid]   : 0.f;
    float precr= (tid < Dd) ? prec[tid] : 0.f;

    // ---- init state + log p(x0) ----
    float lp = 0.f;
    if (tid < Dd){
        float xv = x0[b*Dd + tid];
        ybase[tid] = xv; xcur[tid] = xv;
        lp = -0.5f*xv*xv - 0.5f*LOG2PI_F;
    }
    if (tid == 32){ ybase[Dd] = 0.f; ybase[Dd+1] = 0.f; }
    #pragma unroll
    for (int off=16; off>0; off>>=1) lp += __shfl_down(lp, off);
    if (tid == 0) logpx0_sh = lp;
    __syncthreads();

    const float dt = 1.0f/NSTEPS;

    for (int step=0; step<NSTEPS; ++step){
        float t0 = step*dt;
        for (int stage=0; stage<6; ++stage){
            float cst;
            switch(stage){
                case 0: cst=0.f;      break;
                case 1: cst=0.2f;     break;
                case 2: cst=0.3f;     break;
                case 3: cst=0.8f;     break;
                case 4: cst=8.f/9.f;  break;
                default: cst=1.f;     break;
            }
            float t = t0 + cst*dt;

            // (1) h1 = tanh(W1 x + t u1 + b1)
            float s1 = 0.f;
            {
                const float4* xp = (const float4*)(xcur + (half<<4));
                #pragma unroll
                for (int q=0;q<4;++q){ float4 v=xp[q];
                    s1 += w1r[4*q]*v.x + w1r[4*q+1]*v.y + w1r[4*q+2]*v.z + w1r[4*q+3]*v.w; }
            }
            s1 += __shfl_xor(s1, 1);
            s1 += t*u1r + b1r;
            float h1v = fast_tanh(s1);
            float d1v = 1.f - h1v*h1v;
            if (half == 0){ h1s[row] = h1v; d1s[row] = d1v; }
            __syncthreads();

            // (2) h2 = tanh(W2 h1 + b2) ; qv = (Qm d1)[row]
            float s2 = 0.f, qv = 0.f;
            {
                const float4* hp = (const float4*)(h1s + kbase);
                const float4* dp = (const float4*)(d1s + kbase);
                #pragma unroll
                for (int q=0;q<16;++q){
                    float4 hv = hp[q], dv = dp[q];
                    s2 += w2r[4*q]*hv.x + w2r[4*q+1]*hv.y + w2r[4*q+2]*hv.z + w2r[4*q+3]*hv.w;
                    qv += qr[4*q]*dv.x + qr[4*q+1]*dv.y + qr[4*q+2]*dv.z + qr[4*q+3]*dv.w;
                }
            }
            s2 += __shfl_xor(s2, 1);
            qv += __shfl_xor(qv, 1);
            s2 += b2r;
            float h2v = fast_tanh(s2);
            float d2v = 1.f - h2v*h2v;
            if (half == 0) h2s[row] = h2v;
            float tq = (half==0) ? d2v*qv : 0.f;   // per-row trace contribution
            #pragma unroll
            for (int off=32; off>0; off>>=1) tq += __shfl_xor(tq, off);
            if ((tid & 63) == 0) tpart[tid>>6] = tq;
            __syncthreads();

            // (3) dxdt partials: pout[kseg][orow] = W3[orow, kseg*16:+16] . h2
            {
                float po = 0.f;
                const float4* hp = (const float4*)(h2s + (kseg<<4));
                #pragma unroll
                for (int q=0;q<4;++q){ float4 v=hp[q];
                    po += w3r[4*q]*v.x + w3r[4*q+1]*v.y + w3r[4*q+2]*v.z + w3r[4*q+3]*v.w; }
                pout[kseg][orow] = po;
            }
            __syncthreads();

            // (4) finalize k-vector for this stage
            float trace = tpart[0]+tpart[1]+tpart[2]+tpart[3];
            float dlogp = -trace;
            float kx = 0.f, dkc = 0.f;
            if (tid < Dd){
                kx = b3r;
                #pragma unroll
                for (int s8=0;s8<8;++s8) kx += pout[s8][tid];
                float xv  = xcur[tid];
                float li  = -0.5f*xv*xv - 0.5f*LOG2PI_F;
                float gi  = -precr*xv;
                float omt = 1.f - t;
                dkc = (-0.5f*omt*omt*li - 0.5f*omt*(1.f+t)*gi) * kx;
            }
            #pragma unroll
            for (int off=16; off>0; off>>=1) dkc += __shfl_down(dkc, off);
            if (tid < Dd) karr[stage][tid] = kx;
            if (tid == 0){ karr[stage][Dd] = dlogp; karr[stage][Dd+1] = dkc + (1.f-t)*dlogp; }
            __syncthreads();

            // (5) next stage x, or final y update
            if (stage < 5){
                if (tid < Dd){
                    float k1 = karr[0][tid];
                    float acc = ybase[tid];
                    switch(stage){
                        case 0: acc += dt*(0.2f*k1); break;
                        case 1: acc += dt*(0.075f*k1 + 0.225f*karr[1][tid]); break;
                        case 2: acc += dt*((44.f/45.f)*k1 + (-56.f/15.f)*karr[1][tid] + (32.f/9.f)*karr[2][tid]); break;
                        case 3: acc += dt*((19372.f/6561.f)*k1 + (-25360.f/2187.f)*karr[1][tid]
                                        + (64448.f/6561.f)*karr[2][tid] + (-212.f/729.f)*karr[3][tid]); break;
                        default: acc += dt*((9017.f/3168.f)*k1 + (-355.f/33.f)*karr[1][tid]
                                        + (46732.f/5247.f)*karr[2][tid] + (49.f/176.f)*karr[3][tid]
                                        + (-5103.f/18656.f)*karr[4][tid]); break;
                    }
                    xcur[tid] = acc;
                }
            } else {
                if (tid < Dd+2){
                    float acc = ybase[tid] + dt*((35.f/384.f)*karr[0][tid] + (500.f/1113.f)*karr[2][tid]
                              + (125.f/192.f)*karr[3][tid] + (-2187.f/6784.f)*karr[4][tid]
                              + (11.f/84.f)*karr[5][tid]);
                    ybase[tid] = acc;
                    if (tid < Dd) xcur[tid] = acc;
                }
            }
            __syncthreads();
        }
    }

    // ---- outputs: z (B*D), logp (B), kl (B) ----
    if (tid < Dd) out[b*Dd + tid] = ybase[tid];
    if (tid == 0){
        out[B*Dd + b]     = logpx0_sh + ybase[Dd];
        out[B*Dd + B + b] = ybase[Dd+1];
    }
}

extern "C" void kernel_launch(void* const* d_in, const int* in_sizes, int n_in,
                              void* d_out, int out_size, void* d_ws, size_t ws_size,
                              hipStream_t stream){
    const float* x0   = (const float*)d_in[0];
    const float* W1   = (const float*)d_in[1];
    const float* u1   = (const float*)d_in[2];
    const float* b1   = (const float*)d_in[3];
    const float* W2   = (const float*)d_in[4];
    const float* b2   = (const float*)d_in[5];
    const float* W3   = (const float*)d_in[6];
    const float* b3   = (const float*)d_in[7];
    const float* prec = (const float*)d_in[8];
    float* out = (float*)d_out;
    int B = in_sizes[0] / Dd;

    float* Qm = (float*)d_ws;
    int qm_valid = (ws_size >= (size_t)(Hh*Hh*sizeof(float))) ? 1 : 0;
    if (qm_valid){
        qm_precompute<<<(Hh*Hh+255)/256, 256, 0, stream>>>(W1, W2, W3, Qm);
    }
    vno_main<<<B, 256, 0, stream>>>(x0, W1, u1, b1, W2, b2, W3, b3, prec, Qm, qm_valid, out, B);
}

// Round 2
// 211.247 us; speedup vs baseline: 1.0528x; 1.0528x over previous
//
#include <hip/hip_runtime.h>
#include <math.h>

#define Dd 32
#define Hh 128
#define NSTEPS 8
#define LOG2PI_F 1.8378770664093453f

__device__ __forceinline__ float fast_tanh(float x){
    // tanh(x) = 1 - 2/(exp(2x)+1); exp->inf and ->0 limits give +-1 correctly.
    float e = __expf(2.0f*x);
    return 1.0f - 2.0f*__builtin_amdgcn_rcpf(e + 1.0f);
}

// Qm[j,i] = W2[j,i] * (W1@W3)[i,j]  -> trace(J) = d2^T Qm d1
__global__ void qm_precompute(const float* __restrict__ W1, const float* __restrict__ W2,
                              const float* __restrict__ W3, float* __restrict__ Qm){
    int idx = blockIdx.x*256 + threadIdx.x;
    if (idx >= Hh*Hh) return;
    int j = idx >> 7;
    int i = idx & (Hh-1);
    float m = 0.f;
    #pragma unroll
    for (int d=0; d<Dd; ++d) m += W1[i*Dd+d]*W3[d*Hh+j];
    Qm[j*Hh+i] = m * W2[j*Hh+i];
}

__global__ __launch_bounds__(256,1) void vno_main(
    const float* __restrict__ x0, const float* __restrict__ W1, const float* __restrict__ u1,
    const float* __restrict__ b1, const float* __restrict__ W2, const float* __restrict__ b2,
    const float* __restrict__ W3, const float* __restrict__ b3, const float* __restrict__ prec,
    const float* __restrict__ Qm, int qm_valid, float* __restrict__ out, int B)
{
    const int tid  = threadIdx.x;
    const int b    = blockIdx.x;
    const int row  = tid >> 1;          // 0..127: hidden row owned (2 threads/row)
    const int half = tid & 1;           // K-half for layers 1/2
    const int lane = tid & 63;
    const int wave = tid >> 6;
    const int d    = lane & 31;         // wave0: output element for layer 3
    const int kh   = lane >> 5;         // wave0: K-half for layer 3
    const int srow = row + ((row >= 64) ? 4 : 0);   // +4 skew between halves
    const int kloc = half ? 68 : 0;     // skewed LDS base for h1 reads
    const int k2loc= kh   ? 68 : 0;     // skewed LDS base for h2 reads (wave0)

    __shared__ alignas(16) float xcur[Dd];
    __shared__ alignas(16) float h1s[132];   // [0..63] rows 0..63, [68..131] rows 64..127
    __shared__ alignas(16) float h2s[132];
    __shared__ float redbuf[4][4];

    // ---- register-resident weights ----
    float w1r[16], w2r[64], qr[64], w3r[64];
    float qsum = 0.f;
    {
        const float4* p = (const float4*)(W1 + row*Dd + (half<<4));
        #pragma unroll
        for (int q=0;q<4;++q){ float4 v=p[q]; w1r[4*q]=v.x; w1r[4*q+1]=v.y; w1r[4*q+2]=v.z; w1r[4*q+3]=v.w; }
    }
    {
        const float4* p = (const float4*)(W2 + row*Hh + (half<<6));
        #pragma unroll
        for (int q=0;q<16;++q){ float4 v=p[q]; w2r[4*q]=v.x; w2r[4*q+1]=v.y; w2r[4*q+2]=v.z; w2r[4*q+3]=v.w; }
    }
    if (qm_valid){
        const float4* p = (const float4*)(Qm + row*Hh + (half<<6));
        #pragma unroll
        for (int q=0;q<16;++q){ float4 v=p[q]; qr[4*q]=v.x; qr[4*q+1]=v.y; qr[4*q+2]=v.z; qr[4*q+3]=v.w; }
    } else {
        float w3c[Dd];
        #pragma unroll
        for (int dd=0; dd<Dd; ++dd) w3c[dd] = W3[dd*Hh + row];
        for (int k=0;k<64;++k){
            int i = (half<<6) + k;
            const float4* w1p = (const float4*)(W1 + i*Dd);
            float m = 0.f;
            #pragma unroll
            for (int q=0;q<8;++q){ float4 v=w1p[q]; m += v.x*w3c[4*q] + v.y*w3c[4*q+1] + v.z*w3c[4*q+2] + v.w*w3c[4*q+3]; }
            qr[k] = m * W2[row*Hh + i];
        }
    }
    #pragma unroll
    for (int k=0;k<64;++k) qsum += qr[k];

    if (wave == 0){
        const float4* p = (const float4*)(W3 + d*Hh + (kh<<6));
        #pragma unroll
        for (int q=0;q<16;++q){ float4 v=p[q]; w3r[4*q]=v.x; w3r[4*q+1]=v.y; w3r[4*q+2]=v.z; w3r[4*q+3]=v.w; }
    }

    const float u1r = u1[row], b1r = b1[row], b2r = b2[row];
    float b3r = 0.f, precr = 0.f;
    if (wave == 0){ b3r = b3[d]; precr = prec[d]; }

    // ---- state init (wave0 registers) ----
    float xv = 0.f, yb = 0.f, lp = 0.f;
    if (wave == 0){
        xv = x0[b*Dd + d];
        yb = xv;
        if (kh == 0){ xcur[d] = xv; lp = -0.5f*xv*xv - 0.5f*LOG2PI_F; }
    }
    float acc_ld = 0.f, acc_kltr = 0.f, acc_kl = 0.f;
    float kreg[6];
    #pragma unroll
    for (int s=0;s<6;++s) kreg[s] = 0.f;
    __syncthreads();

    const float dt = 1.0f/NSTEPS;
    const float csts[6] = {0.f, 0.2f, 0.3f, 0.8f, 8.f/9.f, 1.f};
    const float wbs[6]  = {35.f/384.f, 0.f, 500.f/1113.f, 125.f/192.f, -2187.f/6784.f, 11.f/84.f};

    for (int step=0; step<NSTEPS; ++step){
        const float t0 = step*dt;
        #pragma unroll
        for (int stage=0; stage<6; ++stage){
            const float t   = t0 + csts[stage]*dt;
            const float omt = 1.f - t;
            const float wb  = wbs[stage];

            // ---- (1) h1 = tanh(W1 x + t u1 + b1) : 2 threads/row, K=16 each ----
            float ax=0.f, ay=0.f, az=0.f, aw=0.f;
            {
                const float4* xp = (const float4*)xcur;
                #pragma unroll
                for (int q=0;q<4;++q){
                    float4 v = xp[(half<<2)+q];
                    ax += w1r[4*q+0]*v.x; ay += w1r[4*q+1]*v.y;
                    az += w1r[4*q+2]*v.z; aw += w1r[4*q+3]*v.w;
                }
            }
            float s1 = (ax+ay)+(az+aw);
            s1 += __shfl_xor(s1, 1);
            s1 += t*u1r + b1r;
            float h1v = fast_tanh(s1);
            if (half == 0) h1s[srow] = h1v;
            __syncthreads();   // barrier 1

            // ---- (2) h2 = tanh(W2 h1 + b2);  qv = qsum - sum(qr * h1^2) ----
            float sx=0.f, sy=0.f, sz=0.f, sw=0.f;
            float qx=0.f, qy=0.f, qz=0.f, qw=0.f;
            {
                const float4* hp = (const float4*)(h1s + kloc);
                #pragma unroll
                for (int q=0;q<16;++q){
                    float4 hv = hp[q];
                    sx += w2r[4*q+0]*hv.x; sy += w2r[4*q+1]*hv.y;
                    sz += w2r[4*q+2]*hv.z; sw += w2r[4*q+3]*hv.w;
                    if (stage != 1){    // b_2 == 0: trace not needed for stage 1
                        qx += qr[4*q+0]*(hv.x*hv.x); qy += qr[4*q+1]*(hv.y*hv.y);
                        qz += qr[4*q+2]*(hv.z*hv.z); qw += qr[4*q+3]*(hv.w*hv.w);
                    }
                }
            }
            float s2 = (sx+sy)+(sz+sw);
            s2 += __shfl_xor(s2, 1);
            s2 += b2r;
            float h2v = fast_tanh(s2);
            if (half == 0) h2s[srow] = h2v;
            if (stage != 1){
                float qh = qsum - ((qx+qy)+(qz+qw));
                float qv = qh + __shfl_xor(qh, 1);      // full-row (Qm d1)[row]
                float d2v = 1.f - h2v*h2v;
                float tq  = d2v*qv;                     // per-row trace contrib (x2 dup)
                acc_ld   += wb*tq;
                acc_kltr += (wb*omt)*tq;
            }
            __syncthreads();   // barrier 2

            // ---- (3) wave0: kx = W3 h2 + b3 ; kl dot terms ; x-update ----
            if (wave == 0){
                float cx=0.f, cy=0.f, cz=0.f, cw=0.f;
                const float4* h2p = (const float4*)(h2s + k2loc);
                #pragma unroll
                for (int q=0;q<16;++q){
                    float4 v = h2p[q];
                    cx += w3r[4*q+0]*v.x; cy += w3r[4*q+1]*v.y;
                    cz += w3r[4*q+2]*v.z; cw += w3r[4*q+3]*v.w;
                }
                float kx = (cx+cy)+(cz+cw);
                kx += __shfl_xor(kx, 32);
                kx += b3r;
                kreg[stage] = kx;
                if (stage != 1){
                    float li = -0.5f*xv*xv - 0.5f*LOG2PI_F;
                    float gi = -precr*xv;
                    float coef = -0.5f*omt*omt*li - 0.5f*omt*(1.f+t)*gi;
                    acc_kl += (wb*coef)*kx;             // x2 dup across kh
                }
                float xn;
                switch(stage){
                    case 0: xn = yb + dt*(0.2f*kreg[0]); break;
                    case 1: xn = yb + dt*(0.075f*kreg[0] + 0.225f*kreg[1]); break;
                    case 2: xn = yb + dt*((44.f/45.f)*kreg[0] + (-56.f/15.f)*kreg[1]
                                       + (32.f/9.f)*kreg[2]); break;
                    case 3: xn = yb + dt*((19372.f/6561.f)*kreg[0] + (-25360.f/2187.f)*kreg[1]
                                       + (64448.f/6561.f)*kreg[2] + (-212.f/729.f)*kreg[3]); break;
                    case 4: xn = yb + dt*((9017.f/3168.f)*kreg[0] + (-355.f/33.f)*kreg[1]
                                       + (46732.f/5247.f)*kreg[2] + (49.f/176.f)*kreg[3]
                                       + (-5103.f/18656.f)*kreg[4]); break;
                    default:
                        yb = yb + dt*((35.f/384.f)*kreg[0] + (500.f/1113.f)*kreg[2]
                                   + (125.f/192.f)*kreg[3] + (-2187.f/6784.f)*kreg[4]
                                   + (11.f/84.f)*kreg[5]);
                        xn = yb; break;
                }
                xv = xn;
                if (kh == 0) xcur[d] = xn;
            }
            __syncthreads();   // barrier 3
        }
    }

    // ---- outputs ----
    if (wave == 0 && kh == 0) out[b*Dd + d] = yb;

    float v0 = acc_ld, v1 = acc_kltr, v2 = (wave==0) ? acc_kl : 0.f, v3 = lp;
    #pragma unroll
    for (int off=1; off<64; off<<=1){
        v0 += __shfl_xor(v0, off);
        v1 += __shfl_xor(v1, off);
        v2 += __shfl_xor(v2, off);
        v3 += __shfl_xor(v3, off);
    }
    if (lane == 0){ redbuf[wave][0]=v0; redbuf[wave][1]=v1; redbuf[wave][2]=v2; redbuf[wave][3]=v3; }
    __syncthreads();
    if (tid == 0){
        float ld=0.f, ktr=0.f, kl=0.f, lps=0.f;
        #pragma unroll
        for (int w=0;w<4;++w){ ld+=redbuf[w][0]; ktr+=redbuf[w][1]; kl+=redbuf[w][2]; lps+=redbuf[w][3]; }
        // each row/elem contribution is duplicated x2 -> 0.5 factors
        float logdet = -0.5f*dt*ld;                 // dt * sum_s b_s * (-trace_s)
        out[B*Dd + b]     = lps + logdet;
        out[B*Dd + B + b] = 0.5f*dt*(kl - ktr);     // dt * sum_s b_s * dkldt_s
    }
}

extern "C" void kernel_launch(void* const* d_in, const int* in_sizes, int n_in,
                              void* d_out, int out_size, void* d_ws, size_t ws_size,
                              hipStream_t stream){
    const float* x0   = (const float*)d_in[0];
    const float* W1   = (const float*)d_in[1];
    const float* u1   = (const float*)d_in[2];
    const float* b1   = (const float*)d_in[3];
    const float* W2   = (const float*)d_in[4];
    const float* b2   = (const float*)d_in[5];
    const float* W3   = (const float*)d_in[6];
    const float* b3   = (const float*)d_in[7];
    const float* prec = (const float*)d_in[8];
    float* out = (float*)d_out;
    int B = in_sizes[0] / Dd;

    float* Qm = (float*)d_ws;
    int qm_valid = (ws_size >= (size_t)(Hh*Hh*sizeof(float))) ? 1 : 0;
    if (qm_valid){
        qm_precompute<<<(Hh*Hh+255)/256, 256, 0, stream>>>(W1, W2, W3, Qm);
    }
    vno_main<<<B, 256, 0, stream>>>(x0, W1, u1, b1, W2, b2, W3, b3, prec, Qm, qm_valid, out, B);
}

// Round 3
// 131.480 us; speedup vs baseline: 1.6916x; 1.6067x over previous
//
#include <hip/hip_runtime.h>
#include <math.h>

#define Dd 32
#define Hh 128
#define NSTEPS 8
#define LOG2PI_F 1.8378770664093453f

__device__ __forceinline__ float fast_tanh(float x){
    // tanh(x) = 1 - 2/(exp(2x)+1); exp->inf and ->0 limits give +-1 correctly.
    float e = __expf(2.0f*x);
    return 1.0f - 2.0f*__builtin_amdgcn_rcpf(e + 1.0f);
}

// Qm[j,i] = W2[j,i] * (W1@W3)[i,j]  -> trace(J) = d2^T Qm d1
__global__ void qm_precompute(const float* __restrict__ W1, const float* __restrict__ W2,
                              const float* __restrict__ W3, float* __restrict__ Qm){
    int idx = blockIdx.x*256 + threadIdx.x;
    if (idx >= Hh*Hh) return;
    int j = idx >> 7;
    int i = idx & (Hh-1);
    float m = 0.f;
    #pragma unroll
    for (int d=0; d<Dd; ++d) m += W1[i*Dd+d]*W3[d*Hh+j];
    Qm[j*Hh+i] = m * W2[j*Hh+i];
}

// 512 threads / block, one sample per block.
// Layers 1-2: 4 threads per hidden row (K split 4 ways) -> small register arrays, no spills.
// Layer 3 + state update: wave 0 only (d = lane&31, K-half = lane>>5).
// 8 waves / 4 SIMDs = 2 waves/SIMD for latency hiding.
__global__ __launch_bounds__(512,2) void vno_main(
    const float* __restrict__ x0, const float* __restrict__ W1, const float* __restrict__ u1,
    const float* __restrict__ b1, const float* __restrict__ W2, const float* __restrict__ b2,
    const float* __restrict__ W3, const float* __restrict__ b3, const float* __restrict__ prec,
    const float* __restrict__ Qm, int qm_valid, float* __restrict__ out, int B)
{
    const int tid  = threadIdx.x;
    const int b    = blockIdx.x;
    const int row  = tid >> 2;          // 0..127: hidden row (4 threads/row)
    const int kq   = tid & 3;           // K-quarter for layers 1/2
    const int lane = tid & 63;
    const int wave = tid >> 6;
    const int d    = lane & 31;         // wave0: output element for layer 3
    const int kh   = lane >> 5;         // wave0: K-half for layer 3
    // chunked LDS layout: h[(r>>5)*36 + (r&31)] -> the 4 K-quarter chunks start
    // at float offsets {0,36,72,108}: distinct banks (offset%32 = 4*kq), broadcast
    // within each 16-lane same-kq group -> conflict-free b128 reads.
    const int cslot = ((row >> 5) * 36) + (row & 31);
    const int rbase = kq * 36;

    __shared__ alignas(16) float xcur[Dd];
    __shared__ alignas(16) float h1s[144];
    __shared__ alignas(16) float h2s[144];
    __shared__ float redbuf[8][4];

    // ---- register-resident weights (fit without spilling) ----
    float w1r[8], w2r[32], qr[32];
    float w3r[64];                      // wave0 only
    {
        const float4* p = (const float4*)(W1 + row*Dd + (kq<<3));
        #pragma unroll
        for (int q=0;q<2;++q){ float4 v=p[q]; w1r[4*q]=v.x; w1r[4*q+1]=v.y; w1r[4*q+2]=v.z; w1r[4*q+3]=v.w; }
    }
    {
        const float4* p = (const float4*)(W2 + row*Hh + (kq<<5));
        #pragma unroll
        for (int q=0;q<8;++q){ float4 v=p[q]; w2r[4*q]=v.x; w2r[4*q+1]=v.y; w2r[4*q+2]=v.z; w2r[4*q+3]=v.w; }
    }
    if (qm_valid){
        const float4* p = (const float4*)(Qm + row*Hh + (kq<<5));
        #pragma unroll
        for (int q=0;q<8;++q){ float4 v=p[q]; qr[4*q]=v.x; qr[4*q+1]=v.y; qr[4*q+2]=v.z; qr[4*q+3]=v.w; }
    } else {
        float w3c[Dd];
        #pragma unroll
        for (int dd=0; dd<Dd; ++dd) w3c[dd] = W3[dd*Hh + row];
        for (int k=0;k<32;++k){
            int i = (kq<<5) + k;
            const float4* w1p = (const float4*)(W1 + i*Dd);
            float m = 0.f;
            #pragma unroll
            for (int q=0;q<8;++q){ float4 v=w1p[q]; m += v.x*w3c[4*q] + v.y*w3c[4*q+1] + v.z*w3c[4*q+2] + v.w*w3c[4*q+3]; }
            qr[k] = m * W2[row*Hh + i];
        }
    }
    float qsum_p = 0.f;
    #pragma unroll
    for (int k=0;k<32;++k) qsum_p += qr[k];

    if (wave == 0){
        const float4* p = (const float4*)(W3 + d*Hh + (kh<<6));
        #pragma unroll
        for (int q=0;q<16;++q){ float4 v=p[q]; w3r[4*q]=v.x; w3r[4*q+1]=v.y; w3r[4*q+2]=v.z; w3r[4*q+3]=v.w; }
    }

    const float u1r = u1[row], b1r = b1[row], b2r = b2[row];
    float b3r = 0.f, precr = 0.f;
    if (wave == 0){ b3r = b3[d]; precr = prec[d]; }

    // ---- state init (wave0 registers) ----
    float xv = 0.f, yb = 0.f, lp = 0.f;
    if (wave == 0){
        xv = x0[b*Dd + d];
        yb = xv;
        if (kh == 0){ xcur[d] = xv; lp = -0.5f*xv*xv - 0.5f*LOG2PI_F; }
    }
    float acc_ld = 0.f, acc_kltr = 0.f, acc_kl = 0.f;
    float kreg[6];
    #pragma unroll
    for (int s=0;s<6;++s) kreg[s] = 0.f;
    __syncthreads();

    const float dt = 1.0f/NSTEPS;
    const float csts[6] = {0.f, 0.2f, 0.3f, 0.8f, 8.f/9.f, 1.f};
    const float wbs[6]  = {35.f/384.f, 0.f, 500.f/1113.f, 125.f/192.f, -2187.f/6784.f, 11.f/84.f};

    for (int step=0; step<NSTEPS; ++step){
        const float t0 = step*dt;
        #pragma unroll
        for (int stage=0; stage<6; ++stage){
            const float t   = t0 + csts[stage]*dt;
            const float omt = 1.f - t;
            const float wb  = wbs[stage];

            // ---- (1) h1 = tanh(W1 x + t u1 + b1) : 4 threads/row, K=8 each ----
            float s1;
            {
                const float4* xp = (const float4*)(xcur + (kq<<3));
                float4 va = xp[0], vb = xp[1];
                float ax = w1r[0]*va.x + w1r[4]*vb.x;
                float ay = w1r[1]*va.y + w1r[5]*vb.y;
                float az = w1r[2]*va.z + w1r[6]*vb.z;
                float aw = w1r[3]*va.w + w1r[7]*vb.w;
                s1 = (ax+ay)+(az+aw);
            }
            s1 += __shfl_xor(s1, 1);
            s1 += __shfl_xor(s1, 2);
            s1 += t*u1r + b1r;
            float h1v = fast_tanh(s1);
            if (kq == 0) h1s[cslot] = h1v;
            __syncthreads();   // barrier 1

            // ---- (2) h2 = tanh(W2 h1 + b2);  qv = qsum - sum(qr * h1^2) ----
            float sx=0.f, sy=0.f, sz=0.f, sw=0.f;
            float qx=0.f, qy=0.f, qz=0.f, qw=0.f;
            {
                const float4* hp = (const float4*)(h1s + rbase);
                #pragma unroll
                for (int q=0;q<8;++q){
                    float4 hv = hp[q];
                    sx += w2r[4*q+0]*hv.x; sy += w2r[4*q+1]*hv.y;
                    sz += w2r[4*q+2]*hv.z; sw += w2r[4*q+3]*hv.w;
                    if (stage != 1){    // b_2 == 0: trace not needed for stage 1
                        qx += qr[4*q+0]*(hv.x*hv.x); qy += qr[4*q+1]*(hv.y*hv.y);
                        qz += qr[4*q+2]*(hv.z*hv.z); qw += qr[4*q+3]*(hv.w*hv.w);
                    }
                }
            }
            float s2 = (sx+sy)+(sz+sw);
            s2 += __shfl_xor(s2, 1);
            s2 += __shfl_xor(s2, 2);
            s2 += b2r;
            float h2v = fast_tanh(s2);
            if (kq == 0) h2s[cslot] = h2v;
            if (stage != 1){
                float qh = qsum_p - ((qx+qy)+(qz+qw));
                qh += __shfl_xor(qh, 1);
                qh += __shfl_xor(qh, 2);               // full (Qm d1)[row]
                float d2v = 1.f - h2v*h2v;
                float tq  = d2v*qh;                    // per-row trace contrib (x4 dup)
                acc_ld   += wb*tq;
                acc_kltr += (wb*omt)*tq;
            }
            __syncthreads();   // barrier 2

            // ---- (3) wave0: kx = W3 h2 + b3 ; kl dot term ; x-update ----
            if (wave == 0){
                float cx=0.f, cy=0.f, cz=0.f, cw=0.f;
                const float4* p0 = (const float4*)(h2s + (kh<<1)*36);
                const float4* p1 = (const float4*)(h2s + ((kh<<1)+1)*36);
                #pragma unroll
                for (int q=0;q<8;++q){
                    float4 v0 = p0[q];
                    cx += w3r[4*q+0]*v0.x; cy += w3r[4*q+1]*v0.y;
                    cz += w3r[4*q+2]*v0.z; cw += w3r[4*q+3]*v0.w;
                }
                #pragma unroll
                for (int q=0;q<8;++q){
                    float4 v1 = p1[q];
                    cx += w3r[32+4*q+0]*v1.x; cy += w3r[32+4*q+1]*v1.y;
                    cz += w3r[32+4*q+2]*v1.z; cw += w3r[32+4*q+3]*v1.w;
                }
                float kx = (cx+cy)+(cz+cw);
                kx += __shfl_xor(kx, 32);
                kx += b3r;
                kreg[stage] = kx;
                if (stage != 1){
                    float li = -0.5f*xv*xv - 0.5f*LOG2PI_F;
                    float gi = -precr*xv;
                    float coef = -0.5f*omt*omt*li - 0.5f*omt*(1.f+t)*gi;
                    acc_kl += (wb*coef)*kx;             // x2 dup across kh
                }
                float xn;
                switch(stage){
                    case 0: xn = yb + dt*(0.2f*kreg[0]); break;
                    case 1: xn = yb + dt*(0.075f*kreg[0] + 0.225f*kreg[1]); break;
                    case 2: xn = yb + dt*((44.f/45.f)*kreg[0] + (-56.f/15.f)*kreg[1]
                                       + (32.f/9.f)*kreg[2]); break;
                    case 3: xn = yb + dt*((19372.f/6561.f)*kreg[0] + (-25360.f/2187.f)*kreg[1]
                                       + (64448.f/6561.f)*kreg[2] + (-212.f/729.f)*kreg[3]); break;
                    case 4: xn = yb + dt*((9017.f/3168.f)*kreg[0] + (-355.f/33.f)*kreg[1]
                                       + (46732.f/5247.f)*kreg[2] + (49.f/176.f)*kreg[3]
                                       + (-5103.f/18656.f)*kreg[4]); break;
                    default:
                        yb = yb + dt*((35.f/384.f)*kreg[0] + (500.f/1113.f)*kreg[2]
                                   + (125.f/192.f)*kreg[3] + (-2187.f/6784.f)*kreg[4]
                                   + (11.f/84.f)*kreg[5]);
                        xn = yb; break;
                }
                xv = xn;
                if (kh == 0) xcur[d] = xn;
            }
            __syncthreads();   // barrier 3
        }
    }

    // ---- outputs ----
    if (wave == 0 && kh == 0) out[b*Dd + d] = yb;

    float v0 = acc_ld, v1 = acc_kltr, v2 = acc_kl, v3 = lp;
    #pragma unroll
    for (int off=1; off<64; off<<=1){
        v0 += __shfl_xor(v0, off);
        v1 += __shfl_xor(v1, off);
        v2 += __shfl_xor(v2, off);
        v3 += __shfl_xor(v3, off);
    }
    if (lane == 0){ redbuf[wave][0]=v0; redbuf[wave][1]=v1; redbuf[wave][2]=v2; redbuf[wave][3]=v3; }
    __syncthreads();
    if (tid == 0){
        float ld=0.f, ktr=0.f, kl=0.f, lps=0.f;
        #pragma unroll
        for (int w=0;w<8;++w){ ld+=redbuf[w][0]; ktr+=redbuf[w][1]; kl+=redbuf[w][2]; lps+=redbuf[w][3]; }
        // trace contributions duplicated x4 (kq), kl dot duplicated x2 (kh)
        float logdet = -0.25f*dt*ld;                    // dt * sum_s b_s * (-trace_s)
        out[B*Dd + b]     = lps + logdet;
        out[B*Dd + B + b] = dt*(0.5f*kl - 0.25f*ktr);   // dt * sum_s b_s * dkldt_s
    }
}

extern "C" void kernel_launch(void* const* d_in, const int* in_sizes, int n_in,
                              void* d_out, int out_size, void* d_ws, size_t ws_size,
                              hipStream_t stream){
    const float* x0   = (const float*)d_in[0];
    const float* W1   = (const float*)d_in[1];
    const float* u1   = (const float*)d_in[2];
    const float* b1   = (const float*)d_in[3];
    const float* W2   = (const float*)d_in[4];
    const float* b2   = (const float*)d_in[5];
    const float* W3   = (const float*)d_in[6];
    const float* b3   = (const float*)d_in[7];
    const float* prec = (const float*)d_in[8];
    float* out = (float*)d_out;
    int B = in_sizes[0] / Dd;

    float* Qm = (float*)d_ws;
    int qm_valid = (ws_size >= (size_t)(Hh*Hh*sizeof(float))) ? 1 : 0;
    if (qm_valid){
        qm_precompute<<<(Hh*Hh+255)/256, 256, 0, stream>>>(W1, W2, W3, Qm);
    }
    vno_main<<<B, 512, 0, stream>>>(x0, W1, u1, b1, W2, b2, W3, b3, prec, Qm, qm_valid, out, B);
}

// Round 4
// 115.196 us; speedup vs baseline: 1.9307x; 1.1414x over previous
//
#include <hip/hip_runtime.h>
#include <math.h>

#define Dd 32
#define Hh 128
#define NSTEPS 8
#define SPB 16
#define LOG2PI_F 1.8378770664093453f

typedef _Float16 half8_t __attribute__((ext_vector_type(8)));
typedef _Float16 half4_t __attribute__((ext_vector_type(4)));
typedef float f32x4 __attribute__((ext_vector_type(4)));

__device__ __forceinline__ float fast_tanh(float x){
    float e = __expf(2.0f*x);
    return 1.0f - 2.0f*__builtin_amdgcn_rcpf(e + 1.0f);
}

// Qm[j,i] = W2[j,i] * (W1@W3)[i,j]  -> trace(J) = d2^T Qm d1
__global__ void qm_precompute(const float* __restrict__ W1, const float* __restrict__ W2,
                              const float* __restrict__ W3, float* __restrict__ Qm){
    int idx = blockIdx.x*256 + threadIdx.x;
    if (idx >= Hh*Hh) return;
    int j = idx >> 7;
    int i = idx & (Hh-1);
    float m = 0.f;
    #pragma unroll
    for (int d=0; d<Dd; ++d) m += W1[i*Dd+d]*W3[d*Hh+j];
    Qm[j*Hh+i] = m * W2[j*Hh+i];
}

// Swizzled LDS addressing: H arrays are [sample][k] f16, row stride 256B;
// 16B blocks XORed by sample -> <=2-way bank conflicts for both the
// transposed D-frag writes (b64) and B-frag reads (b128).
__device__ __forceinline__ void* haddr(void* base, int nn, int byteoff){
    return (void*)((char*)base + nn*256 + (byteoff ^ (nn<<4)));
}
__device__ __forceinline__ void* xaddr(void* base, int nn, int byteoff){
    return (void*)((char*)base + nn*64 + (byteoff ^ ((nn&3)<<4)));
}

// 512 threads = 8 waves; 16 samples per block; 8 blocks for B=128.
// Wave w owns M-tile w (hidden rows 16w..16w+15) for L1/L2; waves 0-1 own L3 + state.
__global__ __launch_bounds__(512,1) void vno_main(
    const float* __restrict__ x0, const float* __restrict__ W1, const float* __restrict__ u1,
    const float* __restrict__ b1, const float* __restrict__ W2, const float* __restrict__ b2,
    const float* __restrict__ W3, const float* __restrict__ b3, const float* __restrict__ prec,
    const float* __restrict__ Qm, int qm_valid, float* __restrict__ out, int B)
{
    const int tid  = threadIdx.x;
    const int wave = tid >> 6;
    const int lane = tid & 63;
    const int n    = lane & 15;         // sample-in-block (B-frag col / D-frag col / A-frag row)
    const int quad = lane >> 4;         // 0..3
    const int s    = blockIdx.x*SPB + n;  // global sample
    const int arow = wave*16 + n;       // A-fragment row (hidden idx for W1/W2/Qm; <32 for W3)
    const int mep  = wave*16 + quad*4;  // D-fragment row base

    __shared__ alignas(16) _Float16 Xt [SPB*32];    // [n][m] 64B rows, swizzled
    __shared__ alignas(16) _Float16 H1t[SPB*128];   // [n][k] 256B rows, swizzled
    __shared__ alignas(16) _Float16 D1t[SPB*128];
    __shared__ alignas(16) _Float16 H2t[SPB*128];
    __shared__ float redA[8][16];   // acc_ld per wave per sample
    __shared__ float redB[8][16];   // acc_kltr
    __shared__ float redC[2][16];   // acc_kl
    __shared__ float redD[2][16];   // log p(x0)

    // ---- A-fragments (weights), f32 -> f16, register resident ----
    half8_t aW1, aW2[4], aQm[4], aW3[4];
    {
        const float* p = W1 + arow*Dd + quad*8;
        #pragma unroll
        for (int j=0;j<8;++j) aW1[j] = (_Float16)p[j];
    }
    #pragma unroll
    for (int kt=0;kt<4;++kt){
        const float* p = W2 + arow*Hh + kt*32 + quad*8;
        #pragma unroll
        for (int j=0;j<8;++j) aW2[kt][j] = (_Float16)p[j];
    }
    if (qm_valid){
        #pragma unroll
        for (int kt=0;kt<4;++kt){
            const float* p = Qm + arow*Hh + kt*32 + quad*8;
            #pragma unroll
            for (int j=0;j<8;++j) aQm[kt][j] = (_Float16)p[j];
        }
    } else {
        for (int kt=0;kt<4;++kt){
            for (int j=0;j<8;++j){
                int i = kt*32 + quad*8 + j;
                float m = 0.f;
                for (int dd=0; dd<Dd; ++dd) m += W1[i*Dd+dd]*W3[dd*Hh+arow];
                aQm[kt][j] = (_Float16)(m * W2[arow*Hh + i]);
            }
        }
    }
    if (wave < 2){
        #pragma unroll
        for (int kt=0;kt<4;++kt){
            const float* p = W3 + arow*Hh + kt*32 + quad*8;   // arow<32 here
            #pragma unroll
            for (int j=0;j<8;++j) aW3[kt][j] = (_Float16)p[j];
        }
    }

    // ---- epilogue params ----
    float u1e[4], b1e[4], b2e[4];
    #pragma unroll
    for (int r=0;r<4;++r){ u1e[r]=u1[mep+r]; b1e[r]=b1[mep+r]; b2e[r]=b2[mep+r]; }
    float b3e[4], pre[4], xv[4], yb[4], lpl = 0.f;
    float kr[6][4];
    if (wave < 2){
        half4_t px;
        #pragma unroll
        for (int r=0;r<4;++r){
            int m = mep + r;                       // 0..31
            b3e[r] = b3[m]; pre[r] = prec[m];
            float x = (s < B) ? x0[s*Dd + m] : 0.f;
            xv[r] = x; yb[r] = x;
            lpl += -0.5f*x*x - 0.5f*LOG2PI_F;
            px[r] = (_Float16)x;
        }
        *(half4_t*)xaddr(Xt, n, wave*32 + quad*8) = px;
    }
    float accLD = 0.f, accLTR = 0.f, accKL = 0.f;
    __syncthreads();

    const float dt = 1.0f/NSTEPS;
    const float csts[6] = {0.f, 0.2f, 0.3f, 0.8f, 8.f/9.f, 1.f};
    const float wbs[6]  = {35.f/384.f, 0.f, 500.f/1113.f, 125.f/192.f, -2187.f/6784.f, 11.f/84.f};

    for (int step=0; step<NSTEPS; ++step){
        const float t0 = step*dt;
        #pragma unroll
        for (int stage=0; stage<6; ++stage){
            const float t   = t0 + csts[stage]*dt;
            const float omt = 1.f - t;
            const float wb  = wbs[stage];

            // ---- L1: H1 = tanh(W1 @ X + t*u1 + b1), one MFMA per wave ----
            half8_t bx = *(const half8_t*)xaddr(Xt, n, quad*16);
            f32x4 a1 = {0.f,0.f,0.f,0.f};
            a1 = __builtin_amdgcn_mfma_f32_16x16x32_f16(aW1, bx, a1, 0, 0, 0);
            half4_t ph1, pd1;
            #pragma unroll
            for (int r=0;r<4;++r){
                float h = fast_tanh(a1[r] + t*u1e[r] + b1e[r]);
                ph1[r] = (_Float16)h;
                pd1[r] = (_Float16)(1.f - h*h);
            }
            *(half4_t*)haddr(H1t, n, wave*32 + quad*8) = ph1;
            if (stage != 1) *(half4_t*)haddr(D1t, n, wave*32 + quad*8) = pd1;
            __syncthreads();   // barrier B

            // ---- L2: H2 = tanh(W2 @ H1 + b2);  T = Qm @ D1 (trace path) ----
            f32x4 aS = {0.f,0.f,0.f,0.f}, aT = {0.f,0.f,0.f,0.f};
            #pragma unroll
            for (int kt=0;kt<4;++kt){
                half8_t bh = *(const half8_t*)haddr(H1t, n, kt*64 + quad*16);
                aS = __builtin_amdgcn_mfma_f32_16x16x32_f16(aW2[kt], bh, aS, 0, 0, 0);
                if (stage != 1){
                    half8_t bd = *(const half8_t*)haddr(D1t, n, kt*64 + quad*16);
                    aT = __builtin_amdgcn_mfma_f32_16x16x32_f16(aQm[kt], bd, aT, 0, 0, 0);
                }
            }
            half4_t ph2; float tr = 0.f;
            #pragma unroll
            for (int r=0;r<4;++r){
                float h = fast_tanh(aS[r] + b2e[r]);
                ph2[r] = (_Float16)h;
                tr += (1.f - h*h) * aT[r];
            }
            *(half4_t*)haddr(H2t, n, wave*32 + quad*8) = ph2;
            if (stage != 1){
                tr += __shfl_xor(tr, 16);
                tr += __shfl_xor(tr, 32);          // per-sample partial trace over this wave's 16 rows
                accLD  += wb*tr;
                accLTR += (wb*omt)*tr;
            }
            __syncthreads();   // barrier C

            // ---- L3 (waves 0-1): KX = W3 @ H2 + b3 ; kl dot ; x-update ----
            if (wave < 2){
                f32x4 aK = {0.f,0.f,0.f,0.f};
                #pragma unroll
                for (int kt=0;kt<4;++kt){
                    half8_t bh = *(const half8_t*)haddr(H2t, n, kt*64 + quad*16);
                    aK = __builtin_amdgcn_mfma_f32_16x16x32_f16(aW3[kt], bh, aK, 0, 0, 0);
                }
                half4_t px;
                #pragma unroll
                for (int r=0;r<4;++r){
                    float kx = aK[r] + b3e[r];
                    kr[stage][r] = kx;
                    if (stage != 1){
                        float x  = xv[r];
                        float li = -0.5f*x*x - 0.5f*LOG2PI_F;
                        float gi = -pre[r]*x;
                        accKL += wb*(-0.5f*omt*omt*li - 0.5f*omt*(1.f+t)*gi)*kx;
                    }
                    float xn;
                    switch(stage){
                        case 0: xn = yb[r] + dt*(0.2f*kr[0][r]); break;
                        case 1: xn = yb[r] + dt*(0.075f*kr[0][r] + 0.225f*kr[1][r]); break;
                        case 2: xn = yb[r] + dt*((44.f/45.f)*kr[0][r] + (-56.f/15.f)*kr[1][r]
                                              + (32.f/9.f)*kr[2][r]); break;
                        case 3: xn = yb[r] + dt*((19372.f/6561.f)*kr[0][r] + (-25360.f/2187.f)*kr[1][r]
                                              + (64448.f/6561.f)*kr[2][r] + (-212.f/729.f)*kr[3][r]); break;
                        case 4: xn = yb[r] + dt*((9017.f/3168.f)*kr[0][r] + (-355.f/33.f)*kr[1][r]
                                              + (46732.f/5247.f)*kr[2][r] + (49.f/176.f)*kr[3][r]
                                              + (-5103.f/18656.f)*kr[4][r]); break;
                        default:
                            yb[r] = yb[r] + dt*((35.f/384.f)*kr[0][r] + (500.f/1113.f)*kr[2][r]
                                             + (125.f/192.f)*kr[3][r] + (-2187.f/6784.f)*kr[4][r]
                                             + (11.f/84.f)*kr[5][r]);
                            xn = yb[r]; break;
                    }
                    xv[r] = xn;
                    px[r] = (_Float16)xn;
                }
                *(half4_t*)xaddr(Xt, n, wave*32 + quad*8) = px;
            }
            __syncthreads();   // barrier A
        }
    }

    // ---- final reductions & outputs ----
    if (quad == 0){ redA[wave][n] = accLD; redB[wave][n] = accLTR; }
    if (wave < 2){
        float kl2 = accKL;
        kl2 += __shfl_xor(kl2, 16); kl2 += __shfl_xor(kl2, 32);
        float lp2 = lpl;
        lp2 += __shfl_xor(lp2, 16); lp2 += __shfl_xor(lp2, 32);
        if (quad == 0){ redC[wave][n] = kl2; redD[wave][n] = lp2; }
        if (s < B){
            #pragma unroll
            for (int r=0;r<4;++r) out[s*Dd + mep + r] = yb[r];
        }
    }
    __syncthreads();
    if (wave == 0 && quad == 0 && s < B){
        float ld = 0.f, ltr = 0.f;
        #pragma unroll
        for (int w=0;w<8;++w){ ld += redA[w][n]; ltr += redB[w][n]; }
        float kl2 = redC[0][n] + redC[1][n];
        float lp2 = redD[0][n] + redD[1][n];
        out[B*Dd + s]     = lp2 - dt*ld;            // log p(x0) + logdet
        out[B*Dd + B + s] = dt*(kl2 - ltr);         // kl
    }
}

extern "C" void kernel_launch(void* const* d_in, const int* in_sizes, int n_in,
                              void* d_out, int out_size, void* d_ws, size_t ws_size,
                              hipStream_t stream){
    const float* x0   = (const float*)d_in[0];
    const float* W1   = (const float*)d_in[1];
    const float* u1   = (const float*)d_in[2];
    const float* b1   = (const float*)d_in[3];
    const float* W2   = (const float*)d_in[4];
    const float* b2   = (const float*)d_in[5];
    const float* W3   = (const float*)d_in[6];
    const float* b3   = (const float*)d_in[7];
    const float* prec = (const float*)d_in[8];
    float* out = (float*)d_out;
    int B = in_sizes[0] / Dd;

    float* Qm = (float*)d_ws;
    int qm_valid = (ws_size >= (size_t)(Hh*Hh*sizeof(float))) ? 1 : 0;
    if (qm_valid){
        qm_precompute<<<(Hh*Hh+255)/256, 256, 0, stream>>>(W1, W2, W3, Qm);
    }
    int nblk = (B + SPB - 1) / SPB;
    vno_main<<<nblk, 512, 0, stream>>>(x0, W1, u1, b1, W2, b2, W3, b3, prec, Qm, qm_valid, out, B);
}